// Round 14
// baseline (71.973 us; speedup 1.0000x reference)
//
#include <hip/hip_runtime.h>

// B=16, S=256, IN=128, OUT=128, HID=512
// y[b,o] = sum_{k=h*128+i} M[b,k]*W2f[k*128+o] + sum_i sx[b,i]*b2[i*128+o]
//   M[b,h,i] = sum_s h[b,s,h]*x[b,s,i],  h = relu(x@W1+b1);  out = y@Wfc + bfc
// 2 kernels: AB (GEMM1+GEMM2 fused, h in LDS; resets barrier counter),
//            CD (512-block W2 stream -> grid barrier -> final reduce in blocks 0..15).

typedef __attribute__((ext_vector_type(8))) short     s16x8;
typedef __attribute__((ext_vector_type(8))) unsigned short u16x8;
typedef __attribute__((ext_vector_type(4))) float     f32x4;

__device__ __forceinline__ unsigned short f2bf(float f) {
    union { float f; unsigned int u; } v; v.f = f;
    unsigned int r = v.u + 0x7FFFu + ((v.u >> 16) & 1u);   // RNE
    return (unsigned short)(r >> 16);
}
__device__ __forceinline__ float bf2f(unsigned short u) {
    union { unsigned int u; float f; } v; v.u = ((unsigned int)u) << 16;
    return v.f;
}

// ws float offsets
#define OFF_MP   0          // Mp   f32 [2][16][65536] -> 2097152 f
#define OFF_PART 2097152    // part f32 [512][16][128] -> 1048576 f
#define OFF_SXP  3145728    // sxp  f32 [4][16][128]   -> 8192 f
#define OFF_CNT  3153920    // 1 uint barrier counter (reset by k_AB each call)

// ---------- Stage AB (R13-proven): GEMM1 (x@W1 -> h in LDS) + GEMM2 (h^T@x -> Mp) ----------
__global__ __launch_bounds__(256) void k_AB(const float* __restrict__ x,
        const float* __restrict__ W1, const float* __restrict__ b1,
        float* __restrict__ Mp, float* __restrict__ sxp,
        unsigned int* __restrict__ cnt) {
    __shared__ __align__(16) unsigned char smem[87296];
    auto Ws  = (unsigned short (*)[136])(smem);            // [64][136] hid x i
    auto xA  = (unsigned short (*)[136])(smem + 17408);    // [128][136] s x i
    auto xTl = (unsigned short (*)[136])(smem + 52224);    // [128][136] i x s
    auto Wt  = (float (*)[33])(smem + 52224);              // f32 staging (alias xTl)
    float* b1s = (float*)(smem + 87040);
    auto hts = (unsigned short (*)[136])(smem);            // [64][136] alias Ws

    const int tid = threadIdx.x;
    const int b  = blockIdx.x >> 4;
    const int hb = (blockIdx.x >> 1) & 7;
    const int sh = blockIdx.x & 1;

    // reset grid-barrier counter for the k_CD that follows in this call
    if (blockIdx.x == 0 && tid == 0)
        __hip_atomic_store(cnt, 0u, __ATOMIC_RELAXED, __HIP_MEMORY_SCOPE_AGENT);

    // stage xA: x f32 -> bf16, [s 128][i 128]
    {
        const int r = tid >> 1, q = tid & 1;
        const float* xrow = &x[(size_t)(b * 256 + sh * 128 + r) * 128 + q * 64];
        #pragma unroll
        for (int m = 0; m < 8; ++m) {
            const float4 v0 = *(const float4*)&xrow[m * 8];
            const float4 v1 = *(const float4*)&xrow[m * 8 + 4];
            unsigned short t8[8] __attribute__((aligned(16))) = {
                f2bf(v0.x), f2bf(v0.y), f2bf(v0.z), f2bf(v0.w),
                f2bf(v1.x), f2bf(v1.y), f2bf(v1.z), f2bf(v1.w)};
            *(u16x8*)&xA[r][q * 64 + m * 8] = *(u16x8*)t8;
        }
        if (tid < 64) b1s[tid] = b1[hb * 64 + tid];
    }
    // stage Ws = W1T slice [hid 64][i 128] via f32 staging chunks of 32 hid
    for (int hq = 0; hq < 2; ++hq) {
        __syncthreads();
        #pragma unroll
        for (int p = 0; p < 16; ++p) {
            const int flat = p * 256 + tid;
            const int i = flat >> 5, hc = flat & 31;
            Wt[i][hc] = W1[(size_t)i * 512 + hb * 64 + hq * 32 + hc];
        }
        __syncthreads();
        {
            const int h2 = tid >> 3, pt = tid & 7;
            unsigned short t16[16] __attribute__((aligned(16)));
            #pragma unroll
            for (int m = 0; m < 16; ++m)
                t16[m] = f2bf(Wt[pt * 16 + m][h2]);
            *(u16x8*)&Ws[hq * 32 + h2][pt * 16]     = *(u16x8*)&t16[0];
            *(u16x8*)&Ws[hq * 32 + h2][pt * 16 + 8] = *(u16x8*)&t16[8];
        }
    }
    __syncthreads();

    const int w = tid >> 6, lane = tid & 63;
    const int wr = w >> 1, wc = w & 1;
    const int l15 = lane & 15, kl = lane >> 4;
    f32x4 zero = {0.f, 0.f, 0.f, 0.f};

    // GEMM1: C[tok 128][hid 64]; wave tile 64x32
    f32x4 acc[4][2];
    #pragma unroll
    for (int i = 0; i < 4; ++i)
        #pragma unroll
        for (int j = 0; j < 2; ++j) acc[i][j] = zero;
    #pragma unroll
    for (int ks = 0; ks < 4; ++ks) {
        s16x8 a[4], bb[2];
        #pragma unroll
        for (int f = 0; f < 4; ++f)
            a[f] = *(const s16x8*)&xA[wr * 64 + f * 16 + l15][ks * 32 + kl * 8];
        #pragma unroll
        for (int f = 0; f < 2; ++f)
            bb[f] = *(const s16x8*)&Ws[wc * 32 + f * 16 + l15][ks * 32 + kl * 8];
        #pragma unroll
        for (int fr = 0; fr < 4; ++fr)
            #pragma unroll
            for (int fc = 0; fc < 2; ++fc)
                acc[fr][fc] = __builtin_amdgcn_mfma_f32_16x16x32_bf16(a[fr], bb[fc], acc[fr][fc], 0, 0, 0);
    }
    __syncthreads();

    // build xTl (transpose of xA) + sxp partials (hb==0); Wt region is dead
    {
        const int i = tid >> 1, q = tid & 1;
        float sacc = 0.f;
        unsigned short t64[64] __attribute__((aligned(16)));
        #pragma unroll
        for (int m = 0; m < 64; ++m) {
            const unsigned short u = xA[q * 64 + m][i];
            sacc += bf2f(u);
            t64[m] = u;
        }
        #pragma unroll
        for (int v = 0; v < 8; ++v)
            *(u16x8*)&xTl[i][q * 64 + v * 8] = *(u16x8*)&t64[v * 8];
        if (hb == 0)
            sxp[(size_t)((sh * 2 + q) * 16 + b) * 128 + i] = sacc;
    }
    __syncthreads();

    // write hts (relu, bf16, [hid 64][tok 128]) into Ws region (dead after GEMM1)
    #pragma unroll
    for (int fr = 0; fr < 4; ++fr)
        #pragma unroll
        for (int fc = 0; fc < 2; ++fc)
            #pragma unroll
            for (int j = 0; j < 4; ++j) {
                const int tok = wr * 64 + fr * 16 + kl * 4 + j;
                const int hid = wc * 32 + fc * 16 + l15;
                const float v = acc[fr][fc][j] + b1s[hid];
                hts[hid][tok] = f2bf(v > 0.f ? v : 0.f);
            }
    __syncthreads();

    // GEMM2: Mp[sh][b][hb*64+h][i] = hts @ xTl (contract s=128); wave tile 32x64
    f32x4 acc2[2][4];
    #pragma unroll
    for (int i = 0; i < 2; ++i)
        #pragma unroll
        for (int j = 0; j < 4; ++j) acc2[i][j] = zero;
    #pragma unroll
    for (int ks = 0; ks < 4; ++ks) {
        s16x8 a2[2], b2f[4];
        #pragma unroll
        for (int f = 0; f < 2; ++f)
            a2[f] = *(const s16x8*)&hts[wr * 32 + f * 16 + l15][ks * 32 + kl * 8];
        #pragma unroll
        for (int f = 0; f < 4; ++f)
            b2f[f] = *(const s16x8*)&xTl[wc * 64 + f * 16 + l15][ks * 32 + kl * 8];
        #pragma unroll
        for (int fr = 0; fr < 2; ++fr)
            #pragma unroll
            for (int fc = 0; fc < 4; ++fc)
                acc2[fr][fc] = __builtin_amdgcn_mfma_f32_16x16x32_bf16(a2[fr], b2f[fc], acc2[fr][fc], 0, 0, 0);
    }
    const size_t mpbase = (size_t)(sh * 16 + b) * 65536;
    #pragma unroll
    for (int fr = 0; fr < 2; ++fr)
        #pragma unroll
        for (int fc = 0; fc < 4; ++fc)
            #pragma unroll
            for (int j = 0; j < 4; ++j) {
                const int h = hb * 64 + wr * 32 + fr * 16 + kl * 4 + j;
                const int i = wc * 64 + fc * 16 + l15;
                Mp[mpbase + (size_t)h * 128 + i] = acc2[fr][fc][j];
            }
}

// ---------- Stage CD: phase C (512 blocks) -> grid barrier -> phase D (blocks 0..15) ----------
__global__ __launch_bounds__(256) void k_CD(const float* __restrict__ Mp,
        const float* __restrict__ W2, const float* __restrict__ sxp,
        const float* __restrict__ b2, const float* __restrict__ Wfc,
        const float* __restrict__ bfc, float* __restrict__ part,
        float* __restrict__ out, unsigned int* __restrict__ cnt) {
    __shared__ float Ms[16][128];
    __shared__ float sh2[2][128];
    __shared__ float sxs[128];
    __shared__ float ysum[128];
    __shared__ float ysh[128];
    const int tid = threadIdx.x;
    const int p = blockIdx.x;

    // ---- phase C (R13-proven) ----
    {
        const int k0 = p * 128;
        #pragma unroll
        for (int r = 0; r < 8; ++r) {
            const int flat = r * 256 + tid;
            const int b = flat >> 7, kk = flat & 127;
            Ms[b][kk] = Mp[(size_t)b * 65536 + k0 + kk]
                      + Mp[(size_t)(16 + b) * 65536 + k0 + kk];
        }
        __syncthreads();
        const int o4 = (tid & 31) * 4;
        const int g  = tid >> 5;
        float4 a0 = {0.f, 0.f, 0.f, 0.f}, a1 = a0;
        #pragma unroll 8
        for (int kk = 0; kk < 128; ++kk) {
            const float4 wv = *(const float4*)&W2[(size_t)(k0 + kk) * 128 + o4];
            const float m0 = Ms[g * 2][kk], m1 = Ms[g * 2 + 1][kk];
            a0.x += m0 * wv.x; a0.y += m0 * wv.y; a0.z += m0 * wv.z; a0.w += m0 * wv.w;
            a1.x += m1 * wv.x; a1.y += m1 * wv.y; a1.z += m1 * wv.z; a1.w += m1 * wv.w;
        }
        *(float4*)&part[(size_t)(p * 16 + g * 2) * 128 + o4]     = a0;
        *(float4*)&part[(size_t)(p * 16 + g * 2 + 1) * 128 + o4] = a1;
    }

    // ---- grid barrier: all 512 signal; blocks >=16 retire; 0..15 wait ----
    __syncthreads();
    if (tid == 0) {
        __threadfence();
        __hip_atomic_fetch_add(cnt, 1u, __ATOMIC_ACQ_REL, __HIP_MEMORY_SCOPE_AGENT);
    }
    if (p >= 16) return;
    if (tid == 0) {
        long spins = 0;
        while (__hip_atomic_load(cnt, __ATOMIC_ACQUIRE, __HIP_MEMORY_SCOPE_AGENT) < 512u) {
            __builtin_amdgcn_s_sleep(2);
            if (++spins > (1L << 26)) break;   // safety; co-residency not even required
        }
    }
    __syncthreads();

    // ---- phase D (blocks 0..15; 2 groups x 128 lanes) ----
    {
        const int b = p;
        const int t = tid & 127;
        const int g = tid >> 7;
        float y = 0.f;
        #pragma unroll 8
        for (int pp = g * 256; pp < g * 256 + 256; ++pp)
            y += part[(size_t)(pp * 16 + b) * 128 + t];
        sh2[g][t] = y;
        __syncthreads();
        if (g == 0) {
            ysum[t] = sh2[0][t] + sh2[1][t];
            sxs[t] = sxp[(size_t)(0 * 16 + b) * 128 + t] + sxp[(size_t)(1 * 16 + b) * 128 + t]
                   + sxp[(size_t)(2 * 16 + b) * 128 + t] + sxp[(size_t)(3 * 16 + b) * 128 + t];
        }
        __syncthreads();
        float yb = 0.f;
        #pragma unroll 8
        for (int i = g * 64; i < g * 64 + 64; ++i)
            yb += sxs[i] * b2[i * 128 + t];
        sh2[g][t] = yb;
        __syncthreads();
        if (g == 0) ysh[t] = ysum[t] + sh2[0][t] + sh2[1][t];
        __syncthreads();
        float f = 0.f;
        #pragma unroll 8
        for (int oo = g * 64; oo < g * 64 + 64; ++oo)
            f += ysh[oo] * Wfc[oo * 128 + t];
        sh2[g][t] = f;
        __syncthreads();
        if (g == 0)
            out[b * 128 + t] = bfc[t] + sh2[0][t] + sh2[1][t];
    }
}

extern "C" void kernel_launch(void* const* d_in, const int* in_sizes, int n_in,
                              void* d_out, int out_size, void* d_ws, size_t ws_size,
                              hipStream_t stream) {
    const float* x   = (const float*)d_in[0];
    const float* W1  = (const float*)d_in[1];
    const float* b1  = (const float*)d_in[2];
    const float* W2  = (const float*)d_in[3];
    const float* b2  = (const float*)d_in[4];
    const float* Wfc = (const float*)d_in[5];
    const float* bfc = (const float*)d_in[6];
    float* ws  = (float*)d_ws;
    float* Mp   = ws + OFF_MP;
    float* part = ws + OFF_PART;
    float* sxp  = ws + OFF_SXP;
    unsigned int* cnt = (unsigned int*)(ws + OFF_CNT);
    float* out  = (float*)d_out;

    k_AB<<<256, 256, 0, stream>>>(x, W1, b1, Mp, sxp, cnt);
    k_CD<<<512, 256, 0, stream>>>(Mp, W2, sxp, b2, Wfc, bfc, part, out, cnt);
}

// Round 15
// 32.072 us; speedup vs baseline: 2.2441x; 2.2441x over previous
//
#include <hip/hip_runtime.h>

// B=16, S=256, IN=128, OUT=128, HID=512
// y[b,o] = sum_{k=h*128+i} M[b,k]*W2f[k*128+o] + sum_i sx[b,i]*b2[i*128+o]
//   M[b,h,i] = sum_s h[b,s,h]*x[b,s,i],  h = relu(x@W1+b1);  out = y@Wfc + bfc
// 3 kernels (R13 structure): AB (GEMM1+GEMM2 fused MFMA), C (8-deep staged W2 stream),
//                            D (final reduce, 1024 thr).

typedef __attribute__((ext_vector_type(8))) short     s16x8;
typedef __attribute__((ext_vector_type(8))) unsigned short u16x8;
typedef __attribute__((ext_vector_type(4))) float     f32x4;

__device__ __forceinline__ unsigned short f2bf(float f) {
    union { float f; unsigned int u; } v; v.f = f;
    unsigned int r = v.u + 0x7FFFu + ((v.u >> 16) & 1u);   // RNE
    return (unsigned short)(r >> 16);
}
__device__ __forceinline__ float bf2f(unsigned short u) {
    union { unsigned int u; float f; } v; v.u = ((unsigned int)u) << 16;
    return v.f;
}

// ws float offsets
#define OFF_MP   0          // Mp   f32 [2][16][65536] -> 2097152 f
#define OFF_PART 2097152    // part f32 [512][16][128] -> 1048576 f
#define OFF_SXP  3145728    // sxp  f32 [4][16][128]   -> 8192 f

// ---------- Stage AB (R13-proven): GEMM1 (x@W1 -> h in LDS) + GEMM2 (h^T@x -> Mp) ----------
__global__ __launch_bounds__(256) void k_AB(const float* __restrict__ x,
        const float* __restrict__ W1, const float* __restrict__ b1,
        float* __restrict__ Mp, float* __restrict__ sxp) {
    __shared__ __align__(16) unsigned char smem[87296];
    auto Ws  = (unsigned short (*)[136])(smem);            // [64][136] hid x i
    auto xA  = (unsigned short (*)[136])(smem + 17408);    // [128][136] s x i
    auto xTl = (unsigned short (*)[136])(smem + 52224);    // [128][136] i x s
    auto Wt  = (float (*)[33])(smem + 52224);              // f32 staging (alias xTl)
    float* b1s = (float*)(smem + 87040);
    auto hts = (unsigned short (*)[136])(smem);            // [64][136] alias Ws

    const int tid = threadIdx.x;
    const int b  = blockIdx.x >> 4;
    const int hb = (blockIdx.x >> 1) & 7;
    const int sh = blockIdx.x & 1;

    {
        const int r = tid >> 1, q = tid & 1;
        const float* xrow = &x[(size_t)(b * 256 + sh * 128 + r) * 128 + q * 64];
        #pragma unroll
        for (int m = 0; m < 8; ++m) {
            const float4 v0 = *(const float4*)&xrow[m * 8];
            const float4 v1 = *(const float4*)&xrow[m * 8 + 4];
            unsigned short t8[8] __attribute__((aligned(16))) = {
                f2bf(v0.x), f2bf(v0.y), f2bf(v0.z), f2bf(v0.w),
                f2bf(v1.x), f2bf(v1.y), f2bf(v1.z), f2bf(v1.w)};
            *(u16x8*)&xA[r][q * 64 + m * 8] = *(u16x8*)t8;
        }
        if (tid < 64) b1s[tid] = b1[hb * 64 + tid];
    }
    for (int hq = 0; hq < 2; ++hq) {
        __syncthreads();
        #pragma unroll
        for (int p = 0; p < 16; ++p) {
            const int flat = p * 256 + tid;
            const int i = flat >> 5, hc = flat & 31;
            Wt[i][hc] = W1[(size_t)i * 512 + hb * 64 + hq * 32 + hc];
        }
        __syncthreads();
        {
            const int h2 = tid >> 3, pt = tid & 7;
            unsigned short t16[16] __attribute__((aligned(16)));
            #pragma unroll
            for (int m = 0; m < 16; ++m)
                t16[m] = f2bf(Wt[pt * 16 + m][h2]);
            *(u16x8*)&Ws[hq * 32 + h2][pt * 16]     = *(u16x8*)&t16[0];
            *(u16x8*)&Ws[hq * 32 + h2][pt * 16 + 8] = *(u16x8*)&t16[8];
        }
    }
    __syncthreads();

    const int w = tid >> 6, lane = tid & 63;
    const int wr = w >> 1, wc = w & 1;
    const int l15 = lane & 15, kl = lane >> 4;
    f32x4 zero = {0.f, 0.f, 0.f, 0.f};

    // GEMM1: C[tok 128][hid 64]; wave tile 64x32
    f32x4 acc[4][2];
    #pragma unroll
    for (int i = 0; i < 4; ++i)
        #pragma unroll
        for (int j = 0; j < 2; ++j) acc[i][j] = zero;
    #pragma unroll
    for (int ks = 0; ks < 4; ++ks) {
        s16x8 a[4], bb[2];
        #pragma unroll
        for (int f = 0; f < 4; ++f)
            a[f] = *(const s16x8*)&xA[wr * 64 + f * 16 + l15][ks * 32 + kl * 8];
        #pragma unroll
        for (int f = 0; f < 2; ++f)
            bb[f] = *(const s16x8*)&Ws[wc * 32 + f * 16 + l15][ks * 32 + kl * 8];
        #pragma unroll
        for (int fr = 0; fr < 4; ++fr)
            #pragma unroll
            for (int fc = 0; fc < 2; ++fc)
                acc[fr][fc] = __builtin_amdgcn_mfma_f32_16x16x32_bf16(a[fr], bb[fc], acc[fr][fc], 0, 0, 0);
    }
    __syncthreads();

    // build xTl (transpose of xA) + sxp partials (hb==0); Wt region is dead
    {
        const int i = tid >> 1, q = tid & 1;
        float sacc = 0.f;
        unsigned short t64[64] __attribute__((aligned(16)));
        #pragma unroll
        for (int m = 0; m < 64; ++m) {
            const unsigned short u = xA[q * 64 + m][i];
            sacc += bf2f(u);
            t64[m] = u;
        }
        #pragma unroll
        for (int v = 0; v < 8; ++v)
            *(u16x8*)&xTl[i][q * 64 + v * 8] = *(u16x8*)&t64[v * 8];
        if (hb == 0)
            sxp[(size_t)((sh * 2 + q) * 16 + b) * 128 + i] = sacc;
    }
    __syncthreads();

    // write hts (relu, bf16, [hid 64][tok 128]) into Ws region
    #pragma unroll
    for (int fr = 0; fr < 4; ++fr)
        #pragma unroll
        for (int fc = 0; fc < 2; ++fc)
            #pragma unroll
            for (int j = 0; j < 4; ++j) {
                const int tok = wr * 64 + fr * 16 + kl * 4 + j;
                const int hid = wc * 32 + fc * 16 + l15;
                const float v = acc[fr][fc][j] + b1s[hid];
                hts[hid][tok] = f2bf(v > 0.f ? v : 0.f);
            }
    __syncthreads();

    // GEMM2: Mp[sh][b][hb*64+h][i] = hts @ xTl; wave tile 32x64
    f32x4 acc2[2][4];
    #pragma unroll
    for (int i = 0; i < 2; ++i)
        #pragma unroll
        for (int j = 0; j < 4; ++j) acc2[i][j] = zero;
    #pragma unroll
    for (int ks = 0; ks < 4; ++ks) {
        s16x8 a2[2], b2f[4];
        #pragma unroll
        for (int f = 0; f < 2; ++f)
            a2[f] = *(const s16x8*)&hts[wr * 32 + f * 16 + l15][ks * 32 + kl * 8];
        #pragma unroll
        for (int f = 0; f < 4; ++f)
            b2f[f] = *(const s16x8*)&xTl[wc * 64 + f * 16 + l15][ks * 32 + kl * 8];
        #pragma unroll
        for (int fr = 0; fr < 2; ++fr)
            #pragma unroll
            for (int fc = 0; fc < 4; ++fc)
                acc2[fr][fc] = __builtin_amdgcn_mfma_f32_16x16x32_bf16(a2[fr], b2f[fc], acc2[fr][fc], 0, 0, 0);
    }
    const size_t mpbase = (size_t)(sh * 16 + b) * 65536;
    #pragma unroll
    for (int fr = 0; fr < 2; ++fr)
        #pragma unroll
        for (int fc = 0; fc < 4; ++fc)
            #pragma unroll
            for (int j = 0; j < 4; ++j) {
                const int h = hb * 64 + wr * 32 + fr * 16 + kl * 4 + j;
                const int i = wc * 64 + fc * 16 + l15;
                Mp[mpbase + (size_t)h * 128 + i] = acc2[fr][fc][j];
            }
}

// ---------- Stage C: y-partials = Ms @ W2-rows, K=128/block, 512 blocks ----------
// Warp wb owns b-rows wb*4..+3; 64 lanes cover o via float2 (512 B/wave, no dup).
// W2 loads explicitly staged 8-deep (wbuf[8]) to force 8 outstanding loads.
__global__ __launch_bounds__(256) void k_C(const float* __restrict__ Mp,
        const float* __restrict__ W2, float* __restrict__ part) {
    __shared__ float Ms[16][128];
    const int tid = threadIdx.x;
    const int p = blockIdx.x;
    const int k0 = p * 128;
    #pragma unroll
    for (int r = 0; r < 8; ++r) {
        const int flat = r * 256 + tid;
        const int b = flat >> 7, kk = flat & 127;
        Ms[b][kk] = Mp[(size_t)b * 65536 + k0 + kk]
                  + Mp[(size_t)(16 + b) * 65536 + k0 + kk];
    }
    __syncthreads();
    const int lane = tid & 63;
    const int wb   = tid >> 6;          // warp -> 4 b-rows
    const int o2   = lane * 2;
    float2 acc[4] = {{0.f,0.f},{0.f,0.f},{0.f,0.f},{0.f,0.f}};
    float2 wbuf[8];
    for (int kb = 0; kb < 128; kb += 8) {
        #pragma unroll
        for (int u = 0; u < 8; ++u)
            wbuf[u] = *(const float2*)&W2[(size_t)(k0 + kb + u) * 128 + o2];
        #pragma unroll
        for (int u = 0; u < 8; ++u) {
            #pragma unroll
            for (int bb = 0; bb < 4; ++bb) {
                const float m = Ms[wb * 4 + bb][kb + u];
                acc[bb].x += m * wbuf[u].x;
                acc[bb].y += m * wbuf[u].y;
            }
        }
    }
    #pragma unroll
    for (int bb = 0; bb < 4; ++bb)
        *(float2*)&part[(size_t)(p * 16 + wb * 4 + bb) * 128 + o2] = acc[bb];
}

// ---------- Stage D: reduce 512 partials + b2 term + Wfc + bfc (1024 thr, 8 groups) ----------
__global__ __launch_bounds__(1024) void k_D(const float* __restrict__ part,
        const float* __restrict__ sxp, const float* __restrict__ b2,
        const float* __restrict__ Wfc, const float* __restrict__ bfc,
        float* __restrict__ out) {
    __shared__ float sh[8][128];
    __shared__ float sxs[128];
    __shared__ float ysum[128];
    __shared__ float ysh[128];
    const int b = blockIdx.x;
    const int t = threadIdx.x & 127;
    const int g = threadIdx.x >> 7;
    float y = 0.f;
    #pragma unroll 8
    for (int pp = g * 64; pp < g * 64 + 64; ++pp)
        y += part[(size_t)(pp * 16 + b) * 128 + t];
    sh[g][t] = y;
    __syncthreads();
    if (g == 0) {
        float yy = sh[0][t];
        #pragma unroll
        for (int j = 1; j < 8; ++j) yy += sh[j][t];
        ysum[t] = yy;
        sxs[t] = sxp[(size_t)(0 * 16 + b) * 128 + t] + sxp[(size_t)(1 * 16 + b) * 128 + t]
               + sxp[(size_t)(2 * 16 + b) * 128 + t] + sxp[(size_t)(3 * 16 + b) * 128 + t];
    }
    __syncthreads();
    float yb = 0.f;
    #pragma unroll
    for (int i = g * 16; i < g * 16 + 16; ++i)
        yb += sxs[i] * b2[i * 128 + t];
    sh[g][t] = yb;
    __syncthreads();
    if (g == 0) {
        float yy = ysum[t];
        #pragma unroll
        for (int j = 0; j < 8; ++j) yy += sh[j][t];
        ysh[t] = yy;
    }
    __syncthreads();
    float f = 0.f;
    #pragma unroll
    for (int oo = g * 16; oo < g * 16 + 16; ++oo)
        f += ysh[oo] * Wfc[oo * 128 + t];
    sh[g][t] = f;
    __syncthreads();
    if (g == 0) {
        float s = bfc[t];
        #pragma unroll
        for (int j = 0; j < 8; ++j) s += sh[j][t];
        out[b * 128 + t] = s;
    }
}

extern "C" void kernel_launch(void* const* d_in, const int* in_sizes, int n_in,
                              void* d_out, int out_size, void* d_ws, size_t ws_size,
                              hipStream_t stream) {
    const float* x   = (const float*)d_in[0];
    const float* W1  = (const float*)d_in[1];
    const float* b1  = (const float*)d_in[2];
    const float* W2  = (const float*)d_in[3];
    const float* b2  = (const float*)d_in[4];
    const float* Wfc = (const float*)d_in[5];
    const float* bfc = (const float*)d_in[6];
    float* ws  = (float*)d_ws;
    float* Mp   = ws + OFF_MP;
    float* part = ws + OFF_PART;
    float* sxp  = ws + OFF_SXP;
    float* out  = (float*)d_out;

    k_AB<<<256, 256, 0, stream>>>(x, W1, b1, Mp, sxp);
    k_C <<<512, 256, 0, stream>>>(Mp, W2, part);
    k_D <<<16, 1024, 0, stream>>>(part, sxp, b2, Wfc, bfc, out);
}